// Round 10
// baseline (222.198 us; speedup 1.0000x reference)
//
#include <hip/hip_runtime.h>
#include <hip/hip_bf16.h>
#include <stdint.h>

#define BB 2
#define NN 2048
#define CC 1024
#define HH 16
#define DD 64
#define C3 3072

typedef __attribute__((ext_vector_type(8))) short bf16x8;
typedef __attribute__((ext_vector_type(4))) short bf16x4;
typedef __attribute__((ext_vector_type(4))) float f32x4;
typedef __attribute__((ext_vector_type(4))) unsigned short ushort4_t;

__device__ __forceinline__ unsigned short f2bf(float f) {
  union { float f; unsigned u; } v; v.f = f;
  unsigned r = v.u + 0x7FFFu + ((v.u >> 16) & 1u);
  return (unsigned short)(r >> 16);
}

#if __has_builtin(__builtin_amdgcn_exp2f)
#define EXP2(x) __builtin_amdgcn_exp2f(x)
#else
#define EXP2(x) exp2f(x)
#endif

// truncating pack of two f32 -> one VGPR holding {lo16=hi(a), hi16=hi(b)}
__device__ __forceinline__ unsigned pack_bf2(float a, float b) {
  union { float f; unsigned u; } ua, ub; ua.f = a; ub.f = b;
#if __has_builtin(__builtin_amdgcn_perm)
  return __builtin_amdgcn_perm(ub.u, ua.u, 0x07060302u);
#else
  return (ua.u >> 16) | (ub.u & 0xFFFF0000u);
#endif
}

// 0.125 (1/sqrt(D)) * log2(e): folded into Q so softmax is raw v_exp_f32 (2^x)
#define QSCALE 0.18033688f

// async global->LDS, 16B per lane; LDS dest must be wave-uniform base + lane*16
#define GLDS(g, l) __builtin_amdgcn_global_load_lds( \
    (const __attribute__((address_space(1))) void*)(g), \
    (__attribute__((address_space(3))) void*)(l), 16, 0, 0)

// ----------------------------------------- merged fp32->bf16 converts (3 bufs)
__global__ __launch_bounds__(256) void k_cvt(
    const float* __restrict__ x, const float* __restrict__ wq,
    const float* __restrict__ wp,
    unsigned short* __restrict__ xb, unsigned short* __restrict__ wqb,
    unsigned short* __restrict__ wpb)
{
  int blk = blockIdx.x;
  const float* s; unsigned short* d; int i;
  if (blk < 4096)      { s = x;  d = xb;  i = blk * 256 + threadIdx.x; }
  else if (blk < 7168) { s = wq; d = wqb; i = (blk - 4096) * 256 + threadIdx.x; }
  else                 { s = wp; d = wpb; i = (blk - 7168) * 256 + threadIdx.x; }
  float4 v = ((const float4*)s)[i];
  ushort4_t o;
  o.x = f2bf(v.x); o.y = f2bf(v.y); o.z = f2bf(v.z); o.w = f2bf(v.w);
  ((ushort4_t*)d)[i] = o;
}

// -------------------------------- GEMM1 fused: qkv = x@Wqkv^T + b, RoPE, pack
// RE-TILED 128(M)x64(N), grid (48,32) = 1536 blocks (~6/CU vs 3): R6 counters
// showed all-pipes-idle latency mush; more independent barrier groups per CU.
// BK=32, double-buffered, one barrier/iter. Epilogue: RoPE in registers,
// wave-private 64x32 LDS tile (staging LDS reused), coalesced b128 stores.
// Region V staged transposed -> writes Vt[bh][d][n] directly.
__global__ __launch_bounds__(256) void k_gemm_qkv(
    const unsigned short* __restrict__ A, const unsigned short* __restrict__ Bt,
    const float* __restrict__ bias,
    const float* __restrict__ cosb, const float* __restrict__ sinb,
    unsigned short* __restrict__ Qg, unsigned short* __restrict__ Kg,
    unsigned short* __restrict__ Vt)
{
  __shared__ __align__(16) unsigned short Sh[12288];  // 24KB: 2x(As 8K + Bs 4K)
  const int tid  = threadIdx.x;
  const int lane = tid & 63;
  const int wave = tid >> 6;
  const int bm = blockIdx.y * 128;
  const int bn = blockIdx.x * 64;
  const int wm = (wave >> 1) * 64;
  const int wn = (wave & 1) * 32;
  const int frow = lane & 15;
  const int fk   = (lane >> 4) * 8;
  const int K = 1024;
  const int NIT = K / 32;

  f32x4 acc[4][2] = {};

  const int arow0 = tid >> 2, cc0 = tid & 3;
  const unsigned short* Arow0 = A  + (size_t)(bm + arow0) * K + cc0 * 8;
  const unsigned short* Arow1 = A  + (size_t)(bm + arow0 + 64) * K + cc0 * 8;
  const unsigned short* Brow  = Bt + (size_t)(bn + arow0) * K + cc0 * 8;   // rows 0..63

  // stage iter 0 into buffer 0
  GLDS(Arow0, Sh + (size_t)tid * 8);
  GLDS(Arow1, Sh + (size_t)(tid + 256) * 8);
  GLDS(Brow,  Sh + 4096 + (size_t)tid * 8);

  for (int it = 0; it < NIT; ++it) {
    const int p = it & 1;
    const unsigned short* As = Sh + p * 6144;
    const unsigned short* Bs = As + 4096;
    __syncthreads();

    if (it + 1 < NIT) {
      const int k1 = (it + 1) * 32;
      unsigned short* An = Sh + (1 - p) * 6144;
      GLDS(Arow0 + k1, An + (size_t)tid * 8);
      GLDS(Arow1 + k1, An + (size_t)(tid + 256) * 8);
      GLDS(Brow  + k1, An + 4096 + (size_t)tid * 8);
    }

    bf16x8 af[4], bfr[2];
#pragma unroll
    for (int t = 0; t < 4; ++t)
      af[t]  = *(const bf16x8*)(As + (wm + t * 16 + frow) * 32 + fk);
#pragma unroll
    for (int t = 0; t < 2; ++t)
      bfr[t] = *(const bf16x8*)(Bs + (wn + t * 16 + frow) * 32 + fk);
#pragma unroll
    for (int mt = 0; mt < 4; ++mt)
#pragma unroll
      for (int nt = 0; nt < 2; ++nt)
        acc[mt][nt] = __builtin_amdgcn_mfma_f32_16x16x32_bf16(af[mt], bfr[nt], acc[mt][nt], 0, 0, 0);
  }
  __syncthreads();   // staging LDS now reusable for epilogue

  const int er0  = (lane >> 4) * 4;
  const int ecol = lane & 15;
  const int region = bn >> 10;                 // wave-uniform: 0=Q,1=K,2=V
  const int gcol0 = bn + wn;                   // 32-aligned
  const int h     = (gcol0 >> 6) & 15;
  const int dbase = gcol0 & 63;                // 0 or 32
  const int rowg0 = bm + wm;                   // wave-uniform
  const int b  = rowg0 >> 11;
  const int n0 = rowg0 & (NN - 1);
  unsigned short* wt = Sh + wave * 2048;       // 64x32 (QK) or 32x64 (V) tile

#pragma unroll
  for (int nt = 0; nt < 2; ++nt) {
    const int cloc = nt * 16 + ecol;           // 0..31 within wave tile
    const int c64  = dbase + cloc;             // d within head
    const float bv = bias[gcol0 + nt * 16 + ecol];
    const int ii  = c64 >> 1;
#pragma unroll
    for (int mt = 0; mt < 4; ++mt)
#pragma unroll
      for (int r = 0; r < 4; ++r) {
        const int ml = mt * 16 + er0 + r;      // row within wave tile
        const int n  = n0 + ml;
        float v = acc[mt][nt][r] + bv;
        float vp = __shfl_xor(v, 1, 64);       // pair partner (d^1)
        if (region == 2) {
          // transposed tile [d 0..31][m 0..63], chunk over m swizzled by d
          wt[cloc * 64 + ((((ml >> 3) ^ (cloc & 7)) << 3) | (ml & 7))] = f2bf(v);
        } else {
          float cth = cosb[n * 32 + ii], sth = sinb[n * 32 + ii];
          float ov = (c64 & 1) ? (vp * sth + v * cth)
                               : (v * cth - vp * sth);
          if (region == 0) ov *= QSCALE;
          // tile [m 0..63][d 0..31], chunk over d swizzled by m
          wt[ml * 32 + ((((cloc >> 3) ^ (ml & 3)) << 3) | (cloc & 7))] = f2bf(ov);
        }
      }
  }

  // coalesced store phase (wave-private tile; in-wave lgkmcnt ordering)
  if (region == 2) {
    const int rr = lane >> 3, cc = lane & 7;
    unsigned short* dst = Vt + ((size_t)(b * HH + h) * DD + dbase) * NN + n0;
#pragma unroll
    for (int it = 0; it < 4; ++it) {
      int dl = it * 8 + rr;                    // 0..31 d-row of tile
      bf16x8 vv = *(const bf16x8*)(wt + dl * 64 + ((cc ^ (dl & 7)) << 3));
      *(bf16x8*)(dst + (size_t)dl * NN + cc * 8) = vv;
    }
  } else {
    const int rr = lane >> 2, cc = lane & 3;
    unsigned short* dqk = ((region == 0) ? Qg : Kg) +
                          ((size_t)(b * HH + h) * NN + n0) * DD + dbase;
#pragma unroll
    for (int it = 0; it < 4; ++it) {
      int ml = it * 16 + rr;                   // 0..63 n-row
      bf16x8 vv = *(const bf16x8*)(wt + ml * 32 + ((cc ^ (ml & 3)) << 3));
      *(bf16x8*)(dqk + (size_t)ml * DD + cc * 8) = vv;
    }
  }
}

// ----------------------------------------------------- flash attention v8
// kv-TILE 128: ONE barrier per 128 kv (16 iters) — amortizes the vmcnt(0)
// barrier drain (R8 accounting: ~3000 cyc/iter stall) over 2x compute.
// Register-P (S^T = K·Q^T -> exp in regs -> 16x16x16 PV), double-buffered
// K[128][64] + V[64][128] (64KB LDS; grid 512 = 2 blocks/CU regardless).
__global__ __launch_bounds__(256) void k_attn(
    const unsigned short* __restrict__ Qg, const unsigned short* __restrict__ Kg,
    const unsigned short* __restrict__ Vtg, unsigned short* __restrict__ Og)
{
  __shared__ __align__(16) unsigned short Ks[2][128 * 64];  // [kv][d] swizzled
  __shared__ __align__(16) unsigned short Vs[2][64 * 128];  // [d][kv] swizzled

  const int tid  = threadIdx.x;
  const int lane = tid & 63;
  const int wave = tid >> 6;
  const int bh = blockIdx.x >> 4;
  const int qt = blockIdx.x & 15;
  const int q0 = qt * 128 + wave * 32;
  const int frow   = lane & 15;
  const int fchunk = lane >> 4;
  const int er0  = (lane >> 4) * 4;
  const int ecol = lane & 15;

  const unsigned short* Qb = Qg  + (size_t)bh * NN * DD;
  const unsigned short* Kb = Kg  + (size_t)bh * NN * DD;
  const unsigned short* Vb = Vtg + (size_t)bh * DD * NN;

  bf16x8 qf[2][2];
#pragma unroll
  for (int m = 0; m < 2; ++m)
#pragma unroll
    for (int kt = 0; kt < 2; ++kt)
      qf[m][kt] = *(const bf16x8*)(Qb + (size_t)(q0 + m * 16 + frow) * DD + kt * 32 + fchunk * 8);

  f32x4 oacc[2][4] = {};
  float lsum[2] = {0.f, 0.f};

  // K staging: rows krow0+32k (k=0..3), 8 chunks/row, chunk ^= row&7
  const int krow0 = tid >> 3;
  const int ksw = ((tid & 7) ^ (krow0 & 7)) * 8;
  // V staging: rows vrow0+16k (k=0..3), 16 chunks/row, low-3-bits swizzle
  const int vrow0 = tid >> 4, vc = tid & 15;
  const int vsw = (((vc ^ (vrow0 & 7)) & 7) | (vc & 8)) * 8;

#pragma unroll
  for (int k = 0; k < 4; ++k) {
    GLDS(Kb + (size_t)(krow0 + 32 * k) * DD + ksw, Ks[0] + (size_t)(tid + 256 * k) * 8);
    GLDS(Vb + (size_t)(vrow0 + 16 * k) * NN + vsw, Vs[0] + (size_t)(tid + 256 * k) * 8);
  }

  for (int t = 0; t < NN / 128; ++t) {
    const int p = t & 1;
    __syncthreads();

    if (t + 1 < NN / 128) {
      const int j = (t + 1) * 128;
#pragma unroll
      for (int k = 0; k < 4; ++k) {
        GLDS(Kb + (size_t)(j + krow0 + 32 * k) * DD + ksw, Ks[1 - p] + (size_t)(tid + 256 * k) * 8);
        GLDS(Vb + (size_t)(vrow0 + 16 * k) * NN + j + vsw, Vs[1 - p] + (size_t)(tid + 256 * k) * 8);
      }
    }

#pragma unroll
    for (int sub = 0; sub < 2; ++sub) {
      // S^T = K Q^T over kv-blocks sub*64 .. sub*64+63
      f32x4 sacc[2][4] = {};
#pragma unroll
      for (int nt = 0; nt < 4; ++nt) {
        int kr = sub * 64 + nt * 16 + frow;
        bf16x8 kf0 = *(const bf16x8*)(Ks[p] + kr * 64 + ((fchunk       ^ (kr & 7)) << 3));
        bf16x8 kf1 = *(const bf16x8*)(Ks[p] + kr * 64 + (((fchunk + 4) ^ (kr & 7)) << 3));
#pragma unroll
        for (int m = 0; m < 2; ++m) {
          sacc[m][nt] = __builtin_amdgcn_mfma_f32_16x16x32_bf16(kf0, qf[m][0], sacc[m][nt], 0, 0, 0);
          sacc[m][nt] = __builtin_amdgcn_mfma_f32_16x16x32_bf16(kf1, qf[m][1], sacc[m][nt], 0, 0, 0);
        }
      }

      // exp in registers; pack to bf16 A-frags; accumulate l per-lane
      bf16x4 pfr[2][4];
#pragma unroll
      for (int m = 0; m < 2; ++m)
#pragma unroll
        for (int nt = 0; nt < 4; ++nt) {
          float e0 = EXP2(sacc[m][nt][0]);
          float e1 = EXP2(sacc[m][nt][1]);
          float e2 = EXP2(sacc[m][nt][2]);
          float e3 = EXP2(sacc[m][nt][3]);
          lsum[m] += (e0 + e1) + (e2 + e3);
          union { unsigned u[2]; bf16x4 v; } pk;
          pk.u[0] = pack_bf2(e0, e1);
          pk.u[1] = pack_bf2(e2, e3);
          pfr[m][nt] = pk.v;
        }

      // O += P V : B-frags are b64 reads from Vs rows (kv sub-half)
#pragma unroll
      for (int dt = 0; dt < 4; ++dt) {
        int vr = dt * 16 + frow;
        bf16x4 vfr[4];
#pragma unroll
        for (int c = 0; c < 4; ++c) {
          int l3 = ((2 * c + (fchunk >> 1)) ^ (vr & 7)) & 7;
          vfr[c] = *(const bf16x4*)(Vs[p] + vr * 128 + ((sub * 8 + l3) << 3) + (fchunk & 1) * 4);
        }
#pragma unroll
        for (int m = 0; m < 2; ++m)
#pragma unroll
          for (int c = 0; c < 4; ++c)
            oacc[m][dt] = __builtin_amdgcn_mfma_f32_16x16x16bf16_1k(pfr[m][c], vfr[c], oacc[m][dt], 0, 0, 0);
      }
    }
  }

  // epilogue: reduce l across quads, then normalize + store
  const int b = bh >> 4;
  const int h = bh & 15;
#pragma unroll
  for (int m = 0; m < 2; ++m) {
    lsum[m] += __shfl_xor(lsum[m], 16, 64);
    lsum[m] += __shfl_xor(lsum[m], 32, 64);   // lane holds l[q=lane&15] of tile m
    float linv[4];
#pragma unroll
    for (int r = 0; r < 4; ++r)
      linv[r] = 1.0f / __shfl(lsum[m], er0 + r, 64);
#pragma unroll
    for (int dt = 0; dt < 4; ++dt)
#pragma unroll
      for (int r = 0; r < 4; ++r) {
        int qrow = q0 + m * 16 + er0 + r;
        int d = dt * 16 + ecol;
        Og[(size_t)(b * NN + qrow) * CC + h * DD + d] = f2bf(oacc[m][dt][r] * linv[r]);
      }
  }
}

// ------------------------------- GEMM2: out = aob @ Wproj^T + b (fp32 out)
// BK=32, double-buffered, one barrier/iter; 64x128 tiles, grid (8,64).
__global__ __launch_bounds__(256) void k_gemm_proj(
    const unsigned short* __restrict__ A, const unsigned short* __restrict__ Bt,
    const float* __restrict__ bias, float* __restrict__ Co)
{
  __shared__ __align__(16) unsigned short As[2][64 * 32];
  __shared__ __align__(16) unsigned short Bs[2][128 * 32];
  const int tid  = threadIdx.x;
  const int lane = tid & 63;
  const int wave = tid >> 6;
  const int bm = blockIdx.y * 64;
  const int bn = blockIdx.x * 128;
  const int wm = (wave >> 1) * 32;
  const int wn = (wave & 1) * 64;
  const int frow = lane & 15;
  const int fk   = (lane >> 4) * 8;
  const int K = 1024;
  const int NIT = K / 32;

  f32x4 acc[2][4] = {};

  const int row0 = tid >> 2, cc0 = tid & 3;
  const unsigned short* Arow  = A  + (size_t)(bm + row0) * K + cc0 * 8;
  const unsigned short* Brow0 = Bt + (size_t)(bn + row0) * K + cc0 * 8;
  const unsigned short* Brow1 = Bt + (size_t)(bn + row0 + 64) * K + cc0 * 8;

  GLDS(Arow,  As[0] + (size_t)tid * 8);
  GLDS(Brow0, Bs[0] + (size_t)tid * 8);
  GLDS(Brow1, Bs[0] + (size_t)(tid + 256) * 8);

  for (int it = 0; it < NIT; ++it) {
    const int p = it & 1;
    __syncthreads();

    if (it + 1 < NIT) {
      const int k1 = (it + 1) * 32;
      GLDS(Arow  + k1, As[1 - p] + (size_t)tid * 8);
      GLDS(Brow0 + k1, Bs[1 - p] + (size_t)tid * 8);
      GLDS(Brow1 + k1, Bs[1 - p] + (size_t)(tid + 256) * 8);
    }

    bf16x8 af[2], bfr[4];
#pragma unroll
    for (int t = 0; t < 2; ++t)
      af[t] = *(const bf16x8*)(As[p] + (wm + t * 16 + frow) * 32 + fk);
#pragma unroll
    for (int t = 0; t < 4; ++t)
      bfr[t] = *(const bf16x8*)(Bs[p] + (wn + t * 16 + frow) * 32 + fk);
#pragma unroll
    for (int mt = 0; mt < 2; ++mt)
#pragma unroll
      for (int nt = 0; nt < 4; ++nt)
        acc[mt][nt] = __builtin_amdgcn_mfma_f32_16x16x32_bf16(af[mt], bfr[nt], acc[mt][nt], 0, 0, 0);
  }

  const int er0  = (lane >> 4) * 4;
  const int ecol = lane & 15;
#pragma unroll
  for (int nt = 0; nt < 4; ++nt) {
    int col = bn + wn + nt * 16 + ecol;
    float bv = bias[col];
#pragma unroll
    for (int mt = 0; mt < 2; ++mt)
#pragma unroll
      for (int r = 0; r < 4; ++r) {
        int rowg = bm + wm + mt * 16 + er0 + r;
        Co[(size_t)rowg * CC + col] = acc[mt][nt][r] + bv;
      }
  }
}

// ---------------------------------------------------------------- launcher
extern "C" void kernel_launch(void* const* d_in, const int* in_sizes, int n_in,
                              void* d_out, int out_size, void* d_ws, size_t ws_size,
                              hipStream_t stream)
{
  const float* x      = (const float*)d_in[0];
  const float* w_qkv  = (const float*)d_in[1];
  const float* b_qkv  = (const float*)d_in[2];
  const float* w_proj = (const float*)d_in[3];
  const float* b_proj = (const float*)d_in[4];
  const float* fcos   = (const float*)d_in[5];
  const float* fsin   = (const float*)d_in[6];
  float* out = (float*)d_out;

  char* ws = (char*)d_ws;
  unsigned short* xb     = (unsigned short*)(ws);              //  8 MB
  unsigned short* wqkvb  = (unsigned short*)(ws + 8388608);    //  6 MB
  unsigned short* wprojb = (unsigned short*)(ws + 14680064);   //  2 MB
  unsigned short* Qb     = (unsigned short*)(ws + 16777216);   //  8 MB
  unsigned short* Kb     = (unsigned short*)(ws + 25165824);   //  8 MB
  unsigned short* Vtb    = (unsigned short*)(ws + 33554432);   //  8 MB
  unsigned short* aob    = (unsigned short*)(ws + 41943040);   //  8 MB

  k_cvt<<<8192, 256, 0, stream>>>(x, w_qkv, w_proj, xb, wqkvb, wprojb);

  k_gemm_qkv<<<dim3(48, 32), 256, 0, stream>>>(xb, wqkvb, b_qkv, fcos, fsin,
                                               Qb, Kb, Vtb);

  k_attn<<<512, 256, 0, stream>>>(Qb, Kb, Vtb, aob);

  k_gemm_proj<<<dim3(8, 64), 256, 0, stream>>>(aob, wprojb, b_proj, out);
}